// Round 15
// baseline (128.826 us; speedup 1.0000x reference)
//
#include <hip/hip_runtime.h>

#define BSZ  8
#define LSEQ 2048
#define DM   256
#define NS   16
#define NC   32          // grid-level chunks (carry 4.2 MB, chain 32)
#define LC   (LSEQ/NC)   // 64 timesteps per chunk
#define NSUB 4           // intra-block sub-chunks (sub-carries live in LDS)
#define LSUB (LC/NSUB)   // 16 timesteps per thread
#define TPB  (NSUB*DM)   // 1024 threads = 16 waves = 4 waves/SIMD

// ---------------------------------------------------------------------------
// Kernel 1: per-(b,chunk) local scan with intra-block L-split.
// Thread (s,i): zero-init scan of its 16 steps -> sub-carry to LDS;
// s==3 group combines 4 sub-carries (in-LDS Horner, a^16) -> global carry.
// 4 waves/SIMD (r6's TLP) without r6's 4x carry traffic / 4x chain.
// carry layout: [b][chunk][n][d]
// ---------------------------------------------------------------------------
__global__ __launch_bounds__(TPB) void k_local(
        const float* __restrict__ x,
        const float* __restrict__ A,
        const float* __restrict__ Bm,
        const float* __restrict__ delta,
        float* __restrict__ carry) {
    __shared__ float sc[NSUB][NS][DM];   // 64 KB
    const int i     = threadIdx.x & (DM - 1);
    const int s     = threadIdx.x >> 8;          // wave-uniform
    const int chunk = blockIdx.x & (NC - 1);
    const int b     = blockIdx.x / NC;

    // issue the 16 x-loads first (independent, in flight together)
    const size_t base = ((size_t)(b * LSEQ + chunk * LC + s * LSUB)) * DM + i;
    float xr[LSUB];
#pragma unroll
    for (int t = 0; t < LSUB; ++t) xr[t] = x[base + (size_t)t * DM];

    const float dt = 1.0f / (1.0f + expf(-delta[i]));
    float a[NS], bb[NS];
#pragma unroll
    for (int n = 0; n < NS; ++n) {
        a[n]  = expf(dt * A[i * NS + n]);
        bb[n] = dt * Bm[i * NS + n];
    }

    float h[NS];
#pragma unroll
    for (int n = 0; n < NS; ++n) h[n] = 0.0f;
#pragma unroll
    for (int t = 0; t < LSUB; ++t) {
        const float xv = xr[t];
#pragma unroll
        for (int n = 0; n < NS; ++n) h[n] = fmaf(a[n], h[n], bb[n] * xv);
    }
#pragma unroll
    for (int n = 0; n < NS; ++n) sc[s][n][i] = h[n];
    __syncthreads();

    if (s == NSUB - 1) {                         // one 256-thread group combines
        float a16[NS];
#pragma unroll
        for (int n = 0; n < NS; ++n) a16[n] = expf(dt * A[i * NS + n] * (float)LSUB);
        float e[NS];
#pragma unroll
        for (int n = 0; n < NS; ++n) e[n] = 0.0f;
#pragma unroll
        for (int u = 0; u < NSUB; ++u) {
#pragma unroll
            for (int n = 0; n < NS; ++n) e[n] = fmaf(a16[n], e[n], sc[u][n][i]);
        }
        float* cp = carry + ((size_t)(b * NC + chunk) * NS) * DM + i;
#pragma unroll
        for (int n = 0; n < NS; ++n) cp[(size_t)n * DM] = e[n];
    }
}

// ---------------------------------------------------------------------------
// Pass 2: per-(b,n,d) prefix over NC carries: load-all (one latency
// round-trip) -> register chain v[32] (static indices) -> store-all.
// ---------------------------------------------------------------------------
__global__ void k_prefix(
        const float* __restrict__ A,
        const float* __restrict__ delta,
        float* __restrict__ carry) {
    const int tid = blockIdx.x * 256 + threadIdx.x;   // 0 .. BSZ*NS*DM-1
    const int d = tid & (DM - 1);
    const int n = (tid >> 8) & (NS - 1);
    const int b = tid >> 12;

    const float dt = 1.0f / (1.0f + expf(-delta[d]));
    const float aL = expf(dt * A[d * NS + n] * (float)LC);

    float* cp = carry + (size_t)b * NC * NS * DM + (size_t)n * DM + d;

    float v[NC];
#pragma unroll
    for (int j = 0; j < NC; ++j) v[j] = cp[(size_t)j * NS * DM];

    float run = 0.0f;
#pragma unroll
    for (int j = 0; j < NC; ++j) {
        const float c = v[j];
        v[j] = run;
        run = fmaf(aL, run, c);
    }

#pragma unroll
    for (int j = 0; j < NC; ++j) cp[(size_t)j * NS * DM] = v[j];
}

// ---------------------------------------------------------------------------
// Kernel 3: seeded replay with intra-block L-split.
// Thread (s,i): zero-scan its 16 steps (recompute sub-carry -> LDS), then
// entry E_s = a16^s (.) h_entry + Horner(sc[u<s]), then seeded scan, y out.
// a16^s via <=3 multiplies (s wave-uniform). Recompute costs VALU, saves the
// 12.6 MB global sub-carry traffic that sank r6.
// ---------------------------------------------------------------------------
__global__ __launch_bounds__(TPB) void k_final(
        const float* __restrict__ x,
        const float* __restrict__ A,
        const float* __restrict__ Bm,
        const float* __restrict__ Cm,
        const float* __restrict__ Dv,
        const float* __restrict__ delta,
        const float* __restrict__ hin,
        float* __restrict__ y) {
    __shared__ float sc[NSUB][NS][DM];   // 64 KB
    const int i     = threadIdx.x & (DM - 1);
    const int s     = threadIdx.x >> 8;          // wave-uniform
    const int chunk = blockIdx.x & (NC - 1);
    const int b     = blockIdx.x / NC;

    const size_t base = ((size_t)(b * LSEQ + chunk * LC + s * LSUB)) * DM + i;
    float xr[LSUB];
#pragma unroll
    for (int t = 0; t < LSUB; ++t) xr[t] = x[base + (size_t)t * DM];

    const float dt = 1.0f / (1.0f + expf(-delta[i]));
    float a[NS], bb[NS];
#pragma unroll
    for (int n = 0; n < NS; ++n) {
        a[n]  = expf(dt * A[i * NS + n]);
        bb[n] = dt * Bm[i * NS + n];
    }

    // zero-init sub-scan (recompute sub-carry)
    float h[NS];
#pragma unroll
    for (int n = 0; n < NS; ++n) h[n] = 0.0f;
#pragma unroll
    for (int t = 0; t < LSUB; ++t) {
        const float xv = xr[t];
#pragma unroll
        for (int n = 0; n < NS; ++n) h[n] = fmaf(a[n], h[n], bb[n] * xv);
    }
#pragma unroll
    for (int n = 0; n < NS; ++n) sc[s][n][i] = h[n];
    __syncthreads();

    // entry state: h = Horner(sc[u<s]) + a16^s * h_entry(chunk)
    {
        float a16[NS];
#pragma unroll
        for (int n = 0; n < NS; ++n) a16[n] = expf(dt * A[i * NS + n] * (float)LSUB);
#pragma unroll
        for (int n = 0; n < NS; ++n) h[n] = 0.0f;
        for (int u = 0; u < s; ++u) {            // s wave-uniform: no divergence
#pragma unroll
            for (int n = 0; n < NS; ++n) h[n] = fmaf(a16[n], h[n], sc[u][n][i]);
        }
        const float* hp = hin + ((size_t)(b * NC + chunk) * NS) * DM + i;
#pragma unroll
        for (int n = 0; n < NS; ++n) {
            float p = hp[(size_t)n * DM];
            for (int u = 0; u < s; ++u) p *= a16[n];   // a16^s * h_entry
            h[n] += p;
        }
    }

    float cc[NS];
#pragma unroll
    for (int n = 0; n < NS; ++n) cc[n] = Cm[i * NS + n];
    const float Dd = Dv[i];

    // seeded scan; y out (strided stores were neutral vs float4 per r9)
#pragma unroll
    for (int t = 0; t < LSUB; ++t) {
        const float xv = xr[t];
        float acc = Dd * xv;
#pragma unroll
        for (int n = 0; n < NS; ++n) {
            h[n] = fmaf(a[n], h[n], bb[n] * xv);
            acc  = fmaf(h[n], cc[n], acc);
        }
        y[base + (size_t)t * DM] = acc;
    }
}

// ---------------------------------------------------------------------------
extern "C" void kernel_launch(void* const* d_in, const int* in_sizes, int n_in,
                              void* d_out, int out_size, void* d_ws, size_t ws_size,
                              hipStream_t stream) {
    const float* x     = (const float*)d_in[0];
    const float* A     = (const float*)d_in[1];
    const float* Bm    = (const float*)d_in[2];
    const float* Cm    = (const float*)d_in[3];
    const float* Dv    = (const float*)d_in[4];
    const float* delta = (const float*)d_in[5];
    float* y = (float*)d_out;

    float* carry = (float*)d_ws;   // BSZ*NC*NS*DM*4 = 4.2 MiB scratch

    dim3 grd(BSZ * NC);                  // 256 blocks x 1024 thr = 4 waves/SIMD
    k_local<<<grd, dim3(TPB), 0, stream>>>(x, A, Bm, delta, carry);

    dim3 grd2((BSZ * NS * DM) / 256);    // 128 blocks
    k_prefix<<<grd2, dim3(256), 0, stream>>>(A, delta, carry);

    k_final<<<grd, dim3(TPB), 0, stream>>>(x, A, Bm, Cm, Dv, delta, carry, y);
}

// Round 16
// 28.438 us; speedup vs baseline: 4.5301x; 4.5301x over previous
//
#include <hip/hip_runtime.h>

#define BSZ  8
#define LSEQ 2048
#define DM   256
#define NS   16
#define NC   32          // chunks along L
#define LC   (LSEQ/NC)   // 64 timesteps per chunk
#define TILE_FLOATS (LC * DM)               // 64 KB LDS tile
#define VEC_ROUNDS  (TILE_FLOATS / 4 / DM)  // 16 float4 ops per thread

// ---------------------------------------------------------------------------
// Kernel 1 (r9 verbatim): per-(b,chunk) local scan, h0=0; emit carry.
// float4 -> LDS staging of the contiguous 64 KB x tile; scan from LDS.
// carry layout: [b][chunk][n][d]  (d contiguous -> coalesced)
// ---------------------------------------------------------------------------
__global__ void k_local(
        const float* __restrict__ x,
        const float* __restrict__ A,
        const float* __restrict__ Bm,
        const float* __restrict__ delta,
        float* __restrict__ carry) {
    __shared__ float lx[TILE_FLOATS];
    const int d     = threadIdx.x;
    const int chunk = blockIdx.x & (NC - 1);
    const int b     = blockIdx.x / NC;

    {   // vectorized stage: 16 rounds x 256 thr x 16 B = 64 KB
        const float4* __restrict__ src =
            (const float4*)(x + ((size_t)(b * LSEQ + chunk * LC)) * DM);
        float4* dst = (float4*)lx;
#pragma unroll
        for (int r = 0; r < VEC_ROUNDS; ++r)
            dst[r * DM + d] = src[r * DM + d];
    }

    const float dt = 1.0f / (1.0f + expf(-delta[d]));
    float a[NS], bb[NS];
#pragma unroll
    for (int n = 0; n < NS; ++n) {
        a[n]  = expf(dt * A[d * NS + n]);
        bb[n] = dt * Bm[d * NS + n];
    }
    __syncthreads();

    float h[NS];
#pragma unroll
    for (int n = 0; n < NS; ++n) h[n] = 0.0f;
#pragma unroll 4
    for (int t = 0; t < LC; ++t) {
        const float xv = lx[t * DM + d];
#pragma unroll
        for (int n = 0; n < NS; ++n) h[n] = fmaf(a[n], h[n], bb[n] * xv);
    }

    float* cp = carry + ((size_t)(b * NC + chunk) * NS) * DM + d;
#pragma unroll
    for (int n = 0; n < NS; ++n) cp[(size_t)n * DM] = h[n];
}

// ---------------------------------------------------------------------------
// Pass 2 — THE ONE CHANGE vs r9: load-all / register-chain / store-all.
// All 32 loads are independent and issued together (one latency round-trip
// instead of 32 serial load->store->fma round-trips). v[32] fully unrolled
// => static indices => registers (rule #20). 256-thr blocks: no VGPR cap.
// ---------------------------------------------------------------------------
__global__ void k_prefix(
        const float* __restrict__ A,
        const float* __restrict__ delta,
        float* __restrict__ carry) {
    const int tid = blockIdx.x * 256 + threadIdx.x;   // 0 .. BSZ*NS*DM-1
    const int d = tid & (DM - 1);
    const int n = (tid >> 8) & (NS - 1);
    const int b = tid >> 12;

    const float dt = 1.0f / (1.0f + expf(-delta[d]));
    const float aL = expf(dt * A[d * NS + n] * (float)LC);

    float* cp = carry + (size_t)b * NC * NS * DM + (size_t)n * DM + d;

    float v[NC];
#pragma unroll
    for (int j = 0; j < NC; ++j) v[j] = cp[(size_t)j * NS * DM];

    float run = 0.0f;
#pragma unroll
    for (int j = 0; j < NC; ++j) {
        const float c = v[j];
        v[j] = run;                    // state entering chunk j
        run = fmaf(aL, run, c);        // state leaving chunk j
    }

#pragma unroll
    for (int j = 0; j < NC; ++j) cp[(size_t)j * NS * DM] = v[j];
}

// ---------------------------------------------------------------------------
// Kernel 3 (r9 verbatim): seeded replay. float4 stage -> LDS; scan; y in
// place in LDS; contiguous float4 store.
// ---------------------------------------------------------------------------
__global__ void k_final(
        const float* __restrict__ x,
        const float* __restrict__ A,
        const float* __restrict__ Bm,
        const float* __restrict__ Cm,
        const float* __restrict__ Dv,
        const float* __restrict__ delta,
        const float* __restrict__ hin,
        float* __restrict__ y) {
    __shared__ float lt[TILE_FLOATS];
    const int d     = threadIdx.x;
    const int chunk = blockIdx.x & (NC - 1);
    const int b     = blockIdx.x / NC;

    const size_t tile_base = ((size_t)(b * LSEQ + chunk * LC)) * DM;
    {   // vectorized stage
        const float4* __restrict__ src = (const float4*)(x + tile_base);
        float4* dst = (float4*)lt;
#pragma unroll
        for (int r = 0; r < VEC_ROUNDS; ++r)
            dst[r * DM + d] = src[r * DM + d];
    }

    const float dt = 1.0f / (1.0f + expf(-delta[d]));
    float a[NS], bb[NS], cc[NS];
#pragma unroll
    for (int n = 0; n < NS; ++n) {
        a[n]  = expf(dt * A[d * NS + n]);
        bb[n] = dt * Bm[d * NS + n];
        cc[n] = Cm[d * NS + n];
    }
    const float Dd = Dv[d];

    float h[NS];
    const float* hp = hin + ((size_t)(b * NC + chunk) * NS) * DM + d;
#pragma unroll
    for (int n = 0; n < NS; ++n) h[n] = hp[(size_t)n * DM];

    __syncthreads();

#pragma unroll 4
    for (int t = 0; t < LC; ++t) {
        const float xv = lt[t * DM + d];
        float acc = Dd * xv;
#pragma unroll
        for (int n = 0; n < NS; ++n) {
            h[n] = fmaf(a[n], h[n], bb[n] * xv);
            acc  = fmaf(h[n], cc[n], acc);
        }
        lt[t * DM + d] = acc;          // in-place: only thread d touches (t,d)
    }
    __syncthreads();

    {   // vectorized store of the y tile
        float4* __restrict__ dst = (float4*)(y + tile_base);
        const float4* src = (const float4*)lt;
#pragma unroll
        for (int r = 0; r < VEC_ROUNDS; ++r)
            dst[r * DM + d] = src[r * DM + d];
    }
}

// ---------------------------------------------------------------------------
extern "C" void kernel_launch(void* const* d_in, const int* in_sizes, int n_in,
                              void* d_out, int out_size, void* d_ws, size_t ws_size,
                              hipStream_t stream) {
    const float* x     = (const float*)d_in[0];
    const float* A     = (const float*)d_in[1];
    const float* Bm    = (const float*)d_in[2];
    const float* Cm    = (const float*)d_in[3];
    const float* Dv    = (const float*)d_in[4];
    const float* delta = (const float*)d_in[5];
    float* y = (float*)d_out;

    float* carry = (float*)d_ws;   // BSZ*NC*NS*DM*4 = 4.2 MiB scratch

    dim3 blk(DM);
    dim3 grd1(BSZ * NC);                 // 256 blocks
    k_local<<<grd1, blk, 0, stream>>>(x, A, Bm, delta, carry);

    dim3 grd2((BSZ * NS * DM) / 256);    // 128 blocks
    k_prefix<<<grd2, dim3(256), 0, stream>>>(A, delta, carry);

    k_final<<<grd1, blk, 0, stream>>>(x, A, Bm, Cm, Dv, delta, carry, y);
}